// Round 7
// baseline (777.137 us; speedup 1.0000x reference)
//
#include <hip/hip_runtime.h>
#include <math.h>

#define NTOK 16384
#define KDIM 2048
#define NEXP 64
#define NW   16
#define BLOCK (NW * 64)          // 1024 threads, 16 waves
#define KC   128                 // k per staged chunk
#define NCH  (KDIM / KC)         // 16 chunks
#define KPW  (KC / NW)           // 8 k per wave per chunk
#define RPAD 68                  // padded row stride for reduce buffer

typedef float f2 __attribute__((ext_vector_type(2)));
typedef float f4 __attribute__((ext_vector_type(4)));

// Block: 64 rows x 64 experts. x staged in LDS (coalesced, XOR-swizzled),
// w per-lane f4 from global (L2-resident). Lane = (rs = lane>>3: 8 rows
// rs*8..+7) x (es = lane&7: 8 experts es*8..+7); acc = f2[8][4] -> v_pk_fma.
// K split: chunk c staged for all, wave wid computes k = c*128 + wid*8 + 0..7.
// Partials tree-reduced via LDS (same code as rounds 3/6), wave-0 epilogue.
__global__ __launch_bounds__(BLOCK, 4) void gate_main(
    const float* __restrict__ x, const float* __restrict__ gw,
    const float* __restrict__ gb, float* __restrict__ out_w,
    float* __restrict__ out_idx, float* __restrict__ ws)
{
    // union: stage[64][128] (8192 f) lives in same bytes as red (8704 f);
    // stage is dead once the k-loop ends (barrier-separated).
    __shared__ float smem[8704 + 256 + 64];
    float* red  = smem;                 // 2 tree-reduce slots, 64*RPAD each
    float* meta = smem + 8704;          // per-row {i1,i2,w1,w2}
    float* scnt = smem + 8960;          // per-expert selection counts
    char*  stb  = (char*)smem;          // staged x tile, byte-addressed

    const int tid   = threadIdx.x;
    const int lane  = tid & 63;
    const int wid   = __builtin_amdgcn_readfirstlane(tid >> 6);
    const int es    = lane & 7;         // expert slot: e = es*8 + j
    const int rs    = lane >> 3;        // row slot:    r = rs*8 + i
    const int rbase = blockIdx.x * 64;

    // ---- staging geometry: thread t holds 2 f4 per chunk (rows t>>5, +32) ----
    const int srow = tid >> 5;                       // 0..31
    const int sk4  = (tid & 31) * 4;                 // k offset 0..124
    const float* sga = x + (size_t)(rbase + srow) * KDIM + sk4;
    const float* sgb = x + (size_t)(rbase + srow + 32) * KDIM + sk4;
    // swizzled LDS byte addr: row*512 + (kbyte ^ ((row&7)<<4))
    char* sda = stb + srow * 512 + ((sk4 * 4) ^ ((srow & 7) << 4));
    char* sdb = stb + (srow + 32) * 512 + ((sk4 * 4) ^ ((srow & 7) << 4));

    f2 a[8][4];                         // a[i][j2] = row rs*8+i, exp es*8+2*j2
#pragma unroll
    for (int i = 0; i < 8; ++i)
#pragma unroll
        for (int j2 = 0; j2 < 4; ++j2) a[i][j2] = (f2){0.f, 0.f};

    // ---- staging prologue: chunk 0 written, chunk 1 in registers ----
    f4 sra = *(const f4*)sga;
    f4 srb = *(const f4*)sgb;
    *(f4*)sda = sra;                    // compiler inserts vmcnt wait
    *(f4*)sdb = srb;
    sra = *(const f4*)(sga + KC);       // chunk 1, in flight during chunk 0
    srb = *(const f4*)(sgb + KC);
    __syncthreads();

    // ---- w prefetch (depth 1), wave-uniform k, per-lane experts ----
    const float* wp = gw + es * 8;
    int kg = wid * KPW;                 // global k for chunk 0
    f4 w0 = *(const f4*)(wp + (size_t)kg * NEXP);
    f4 w1 = *(const f4*)(wp + (size_t)kg * NEXP + 4);

    for (int c = 0; c < NCH; ++c) {
#pragma unroll
        for (int jj = 0; jj < KPW; jj += 2) {
            const int kk = wid * KPW + jj;          // k within staged chunk
            // x: 8 rows x 2 k, conflict-free (xor spreads rows over banks)
            f2 xr[8];
#pragma unroll
            for (int i = 0; i < 8; ++i)
                xr[i] = *(const f2*)(stb + (rs * 8 + i) * 512 +
                                     ((kk * 4) ^ (i << 4)));
#pragma unroll
            for (int t = 0; t < 2; ++t) {
                // next k: +1 within chunk, jump to next chunk at the end
                int knext = (jj == KPW - 2 && t == 1) ? kg + (KC - KPW + 1)
                                                      : kg + 1;
                if (knext >= KDIM) knext = 0;       // clamp (dead final loads)
                f4 nw0 = *(const f4*)(wp + (size_t)knext * NEXP);
                f4 nw1 = *(const f4*)(wp + (size_t)knext * NEXP + 4);
                const f2 wl0 = {w0[0], w0[1]};
                const f2 wl1 = {w0[2], w0[3]};
                const f2 wl2 = {w1[0], w1[1]};
                const f2 wl3 = {w1[2], w1[3]};
#pragma unroll
                for (int i = 0; i < 8; ++i) {
                    const f2 xv = {xr[i][t], xr[i][t]};
                    a[i][0] = __builtin_elementwise_fma(xv, wl0, a[i][0]);
                    a[i][1] = __builtin_elementwise_fma(xv, wl1, a[i][1]);
                    a[i][2] = __builtin_elementwise_fma(xv, wl2, a[i][2]);
                    a[i][3] = __builtin_elementwise_fma(xv, wl3, a[i][3]);
                }
                w0 = nw0; w1 = nw1; kg = knext;
            }
        }
        __syncthreads();                // all waves done reading chunk c
        if (c + 1 < NCH) {
            *(f4*)sda = sra;            // publish chunk c+1
            *(f4*)sdb = srb;
            if (c + 2 < NCH) {          // issue chunk c+2 (hidden under c+1)
                sra = *(const f4*)(sga + (size_t)(c + 2) * KC);
                srb = *(const f4*)(sgb + (size_t)(c + 2) * KC);
            }
        }
        __syncthreads();                // chunk c+1 visible
    }

    // ---- pairwise tree reduce of 16 k-partials via 2 LDS slots ----
    // flat f4 #q = { a[q>>1][(q&1)*2], a[q>>1][(q&1)*2+1] }
    for (int half = NW / 2; half >= 1; half >>= 1) {
        for (int sub = 0; sub < half; sub += 2) {
            const int nslot = (half - sub < 2) ? (half - sub) : 2;
            __syncthreads();
            if (wid >= half + sub && wid < half + sub + nslot) {
                float* dst = red + (size_t)(wid - half - sub) * 64 * RPAD + lane * RPAD;
#pragma unroll
                for (int q = 0; q < 16; ++q) {
                    f4 v = {a[q >> 1][(q & 1) * 2][0], a[q >> 1][(q & 1) * 2][1],
                            a[q >> 1][(q & 1) * 2 + 1][0], a[q >> 1][(q & 1) * 2 + 1][1]};
                    *(f4*)(dst + q * 4) = v;
                }
            }
            __syncthreads();
            if (wid >= sub && wid < sub + nslot) {
                const float* src = red + (size_t)(wid - sub) * 64 * RPAD + lane * RPAD;
#pragma unroll
                for (int q = 0; q < 16; ++q) {
                    f4 v = *(const f4*)(src + q * 4);
                    a[q >> 1][(q & 1) * 2][0]     += v.x;
                    a[q >> 1][(q & 1) * 2][1]     += v.y;
                    a[q >> 1][(q & 1) * 2 + 1][0] += v.z;
                    a[q >> 1][(q & 1) * 2 + 1][1] += v.w;
                }
            }
        }
    }

    // ---- wave 0: transpose outer-product layout -> row-major tile ----
    __syncthreads();
    if (wid == 0) {
#pragma unroll
        for (int i = 0; i < 8; ++i)
#pragma unroll
            for (int j2 = 0; j2 < 4; ++j2)
                *(f2*)(red + (size_t)(rs * 8 + i) * RPAD + es * 8 + j2 * 2) = a[i][j2];
    }
    __syncthreads();

    // ---- epilogue: wave 0, lane = row (proven in rounds 3/6) ----
    int i1 = 0, i2 = 0;
    if (wid == 0) {
        float lg[64];
#pragma unroll
        for (int q = 0; q < 16; ++q) {
            f4 v = *(const f4*)(red + (size_t)lane * RPAD + q * 4);
            lg[q * 4 + 0] = v.x; lg[q * 4 + 1] = v.y;
            lg[q * 4 + 2] = v.z; lg[q * 4 + 3] = v.w;
        }
#pragma unroll
        for (int e = 0; e < NEXP; ++e) lg[e] += gb[e];

        // top-1 then top-2; strict > keeps lowest index on ties (lax.top_k)
        float v1 = lg[0];
#pragma unroll
        for (int e = 1; e < NEXP; ++e)
            if (lg[e] > v1) { v1 = lg[e]; i1 = e; }
        float v2 = -INFINITY;
#pragma unroll
        for (int e = 0; e < NEXP; ++e)
            if (e != i1 && lg[e] > v2) { v2 = lg[e]; i2 = e; }

        // full softmax (aux loss): probs overwrite this lane's tile row
        float ssum = 0.f;
#pragma unroll
        for (int e = 0; e < NEXP; ++e) ssum += __expf(lg[e] - v1);
        const float sinv = 1.f / ssum;
        float* pr = red + (size_t)lane * RPAD;
#pragma unroll
        for (int e = 0; e < NEXP; ++e) pr[e] = __expf(lg[e] - v1) * sinv;

        // renormalized top-2 softmax weights
        const float e2 = __expf(v2 - v1);
        const float wa = 1.f / (1.f + e2);
        f4 m = {(float)i1, (float)i2, wa, e2 * wa};
        ((f4*)meta)[lane] = m;

        *(float2*)(out_idx + (size_t)(rbase + lane) * 2) =
            make_float2((float)i1, (float)i2);

        scnt[lane] = 0.f;
        atomicAdd(&scnt[i1], 1.f);
        atomicAdd(&scnt[i2], 1.f);
    }
    __syncthreads();
    if (wid == 0) {
        // per-expert prob column-sum over this block's 64 rows (lane = expert)
        float ps = 0.f;
#pragma unroll
        for (int r = 0; r < 64; ++r) ps += red[(size_t)r * RPAD + lane];
        atomicAdd(&ws[lane], ps);
        atomicAdd(&ws[NEXP + lane], scnt[lane]);
    }
    __syncthreads();

    // ---- gate-weight store: each wave writes 4 rows, coalesced ----
#pragma unroll
    for (int rr = 0; rr < 4; ++rr) {
        const int r = wid * 4 + rr;
        const f4 m = ((const f4*)meta)[r];      // broadcast read
        const float val = (lane == (int)m.x) ? m.z
                        : ((lane == (int)m.y) ? m.w : 0.f);
        out_w[((size_t)rbase + r) * NEXP + lane] = val;
    }
}

__global__ void gate_aux(const float* __restrict__ ws, float* __restrict__ out_aux)
{
    const int e = threadIdx.x;  // 64 threads
    const float frac = ws[NEXP + e] * (1.f / (float)(NTOK * 2));
    const float mp   = ws[e] * (1.f / (float)NTOK);
    float v = frac * mp * (float)NEXP;
#pragma unroll
    for (int off = 32; off; off >>= 1) v += __shfl_xor(v, off);
    if (e == 0) out_aux[0] = v;
}

extern "C" void kernel_launch(void* const* d_in, const int* in_sizes, int n_in,
                              void* d_out, int out_size, void* d_ws, size_t ws_size,
                              hipStream_t stream) {
    const float* x  = (const float*)d_in[0];
    const float* gw = (const float*)d_in[1];
    const float* gb = (const float*)d_in[2];

    float* out     = (float*)d_out;
    float* out_w   = out;                         // [16384*64]
    float* out_idx = out + (size_t)NTOK * NEXP;   // [16384*2] as floats
    float* out_aux = out_idx + (size_t)NTOK * 2;  // [1]
    float* ws      = (float*)d_ws;                // [128] floats

    (void)hipMemsetAsync(ws, 0, 2 * NEXP * sizeof(float), stream);
    gate_main<<<NTOK / 64, BLOCK, 0, stream>>>(x, gw, gb, out_w, out_idx, ws);
    gate_aux<<<1, 64, 0, stream>>>(ws, out_aux);
}